// Round 13
// baseline (132.589 us; speedup 1.0000x reference)
//
#include <hip/hip_runtime.h>
#include <hip/hip_bf16.h>

#define DIM  512
#define FEAT 64
#define BATCH 2048

#define NTILES 16   // consecutive d per wave-walk

using bf16x8 = __attribute__((ext_vector_type(8))) short;
using f32x4  = __attribute__((ext_vector_type(4))) float;

typedef __attribute__((address_space(3))) float lds_f;
typedef __attribute__((address_space(1))) const float glb_f;

__device__ inline short f2bf(float f) {
    unsigned int u = __float_as_uint(f);
    u += 0x7fffu + ((u >> 16) & 1u);
    return (short)(u >> 16);
}

__device__ inline bf16x8 cvt8(float4 a, float4 b) {
    bf16x8 r;
    r[0] = f2bf(a.x); r[1] = f2bf(a.y); r[2] = f2bf(a.z); r[3] = f2bf(a.w);
    r[4] = f2bf(b.x); r[5] = f2bf(b.y); r[6] = f2bf(b.z); r[7] = f2bf(b.w);
    return r;
}

// ---- pre-pass (R6/R11-verified): W f32 -> bf16 MFMA-fragment layout in ws ----
// ws[short] idx = ((d*8 + g8)*64 + lane)*8, g8 = ks*4 + mt.
__global__ __launch_bounds__(256)
void w_prep(const float* __restrict__ W, short* __restrict__ ws) {
    const int d = blockIdx.x;
    const int t = threadIdx.x;
    const int l = t & 63, g0 = t >> 6;
#pragma unroll
    for (int h = 0; h < 2; ++h) {
        const int g8 = g0 + h * 4;
        const int mt = g8 & 3, ks = g8 >> 2;
        const float* src = W + ((size_t)d * FEAT + mt * 16 + (l & 15)) * FEAT
                             + ks * 32 + (l >> 4) * 8;
        *(bf16x8*)(ws + ((size_t)(d * 8 + g8) * 64 + l) * 8)
            = cvt8(*(const float4*)src, *(const float4*)(src + 4));
    }
}

// ---- main: R9 machinery, transposed walk. Wave owns 16 FIXED rows and walks 16
// consecutive d -> each row is a 4KB sequential run on BOTH read and write sides.
// Wave-private slots, no barriers, counted vmcnt (R9-verified schedule). ----
template<bool PRE>
__global__ __launch_bounds__(256, 2)   // VGPR cap 128; need ~105 (never cap below need)
void split_linear_main(const float* __restrict__ x,
                       const float* __restrict__ W,
                       const short* __restrict__ Wb,
                       const float* __restrict__ bias,
                       float* __restrict__ out)
{
    // x staging AND out-transpose share slots: [wave][slot][16 rows][16 chunks],
    // 16B-chunk XOR(row&7) swizzle on both paths (R8/R9-verified).
    __shared__ float slot[4][2][1024];

    const int id = blockIdx.x;          // 0..1023
    const int dc = id & 31;             // d-chunk; id%8 round-robin -> each XCD owns
                                        // 4 d-chunks (512KB of ws, L2-hot)
    const int rc = id >> 5;             // row-chunk 0..31
    const int d0 = dc * NTILES;
    const int b0 = rc * 64;

    const int tid  = threadIdx.x;
    const int wave = tid >> 6;
    const int lane = tid & 63;
    const int lr   = lane & 15;         // B-col (batch row) / A-row-within-16
    const int lk   = lane >> 4;         // k-group

    const int b0w  = b0 + wave * 16;    // wave's private 16 rows

    // ---- async dense stage (R9 pattern, d advances per tile): 4 instrs x 1KB ----
    auto stage = [&](int s, int t) {
#pragma unroll
        for (int i = 0; i < 4; ++i) {
            const int r = i * 4 + (lane >> 4);
            const int c = (lane & 15) ^ (r & 7);   // pre-swizzled source chunk
            const float* gp = x + ((size_t)(b0w + r) * DIM + d0 + t) * FEAT + c * 4;
            __builtin_amdgcn_global_load_lds((glb_f*)gp,
                                             (lds_f*)&slot[wave][s][i * 256],
                                             16, 0, 0);
        }
    };

    // ---- W fragments + bias for tile t (d = d0+t), dense 1KB loads from ws ----
    auto LOADW = [&](bf16x8 (&wf)[8], f32x4& bv, int t) {
        if (PRE) {
            const short* wq = Wb + (size_t)(d0 + t) * 4096 + lane * 8;
#pragma unroll
            for (int g = 0; g < 8; ++g)
                wf[g] = *(const bf16x8*)(wq + g * 512);
        } else {
            const float* wq = W + (size_t)(d0 + t) * FEAT * FEAT;
#pragma unroll
            for (int g = 0; g < 8; ++g) {
                const int mt = g & 3, ks = g >> 2;
                const float* p = wq + (size_t)(mt * 16 + lr) * FEAT + ks * 32 + lk * 8;
                wf[g] = cvt8(*(const float4*)p, *(const float4*)(p + 4));
            }
        }
        // store-side bias: lane covers out[.., d, lr*4 .. +3] for all its rows
        bv = *(const f32x4*)(bias + (size_t)(d0 + t) * FEAT + lr * 4);
    };

    bf16x8 wfA[8], wfB[8];
    f32x4 bvA, bvB;

    // prologue, issue order pinned: stage(0), LOADW(0), stage(1)
    stage(0, 0);
    __builtin_amdgcn_sched_barrier(0);
    LOADW(wfA, bvA, 0);
    __builtin_amdgcn_sched_barrier(0);
    stage(1, 1);
    __builtin_amdgcn_sched_barrier(0);

    auto BODY = [&](bf16x8 (&wfc)[8], bf16x8 (&wfn)[8], f32x4& bvc, f32x4& bvn, int t) {
        const int s = t & 1;
        // counted vmcnt, R9-verified: retire stage(t)+LOADW(t), keep newest.
        // steady outstanding (old->new): [W(t)9? no:] sg(t)4 ... issue seq per tile:
        //   [tile u-2: W(u-1)9, st(u-2)4, sg(u)4], [tile u-1: W(u)9, st(u-1)4, sg(u+1)4]
        // at tile u: need sg(u), W(u) -> keep st(u-1)4+sg(u+1)4 = vmcnt(8).
        // t=0: [sg0 4, W0 9, sg1 4] -> keep 4. t=15: no sg(16) -> keep st(14)4 = 4.
        if (t == 0 || t == NTILES - 1)
            asm volatile("s_waitcnt vmcnt(4)" ::: "memory");
        else
            asm volatile("s_waitcnt vmcnt(8)" ::: "memory");
        __builtin_amdgcn_sched_barrier(0);

        float* sl = &slot[wave][s][0];
        float4 p0a = *(const float4*)&sl[lr * 64 + (((lk * 2 + 0) ^ (lr & 7)) << 2)];
        float4 p0b = *(const float4*)&sl[lr * 64 + (((lk * 2 + 1) ^ (lr & 7)) << 2)];
        float4 p1a = *(const float4*)&sl[lr * 64 + (((8 + lk * 2 + 0) ^ (lr & 7)) << 2)];
        float4 p1b = *(const float4*)&sl[lr * 64 + (((8 + lk * 2 + 1) ^ (lr & 7)) << 2)];

        bf16x8 af0 = cvt8(p0a, p0b);   // ks = 0
        bf16x8 af1 = cvt8(p1a, p1b);   // ks = 1

        f32x4 acc[4] = {{0.f,0.f,0.f,0.f},{0.f,0.f,0.f,0.f},
                        {0.f,0.f,0.f,0.f},{0.f,0.f,0.f,0.f}};
#pragma unroll
        for (int mt = 0; mt < 4; ++mt)
            acc[mt] = __builtin_amdgcn_mfma_f32_16x16x32_bf16(wfc[mt],     af0, acc[mt], 0, 0, 0);
#pragma unroll
        for (int mt = 0; mt < 4; ++mt)
            acc[mt] = __builtin_amdgcn_mfma_f32_16x16x32_bf16(wfc[4 + mt], af1, acc[mt], 0, 0, 0);
        __builtin_amdgcn_sched_barrier(0);

        // prefetch next tile's W+bias (must precede stores+stage for vmcnt accounting)
        if (t + 1 < NTILES) LOADW(wfn, bvn, t + 1);
        __builtin_amdgcn_sched_barrier(0);

        // ---- transpose INTO the just-consumed slot (wave-private, DS in-order) ----
        // lane (lr,lk), mt holds out[row lr][g = mt*16+lk*4 ..+3] -> chunk c = mt*4+lk
#pragma unroll
        for (int mt = 0; mt < 4; ++mt) {
            const int c  = mt * 4 + lk;
            const int pc = c ^ (lr & 7);           // same swizzle as stage
            *(f32x4*)&sl[lr * 64 + pc * 4] = acc[mt];
        }

        // ---- dense NT store-back + bias: instr j covers rows j*4..+3, 256B/row;
        //      consecutive tiles advance each row's address by +256B (sequential) ----
#pragma unroll
        for (int j = 0; j < 4; ++j) {
            const int rr  = j * 4 + (lane >> 4);
            const int cc  = lane & 15;
            const int pc2 = cc ^ (rr & 7);
            f32x4 v = *(const f32x4*)&sl[rr * 64 + pc2 * 4];
            v += bvc;
            __builtin_nontemporal_store(v,
                (f32x4*)(out + ((size_t)(b0w + rr) * DIM + d0 + t) * FEAT + cc * 4));
        }
        __builtin_amdgcn_sched_barrier(0);   // pin the re-stage below the stores

        if (t + 2 < NTILES)
            stage(s, t + 2);                 // reuse slot s (DMA lands after ds_reads)
        __builtin_amdgcn_sched_barrier(0);
    };

#pragma unroll
    for (int t = 0; t < NTILES; t += 2) {
        BODY(wfA, wfB, bvA, bvB, t);
        BODY(wfB, wfA, bvB, bvA, t + 1);
    }
}

extern "C" void kernel_launch(void* const* d_in, const int* in_sizes, int n_in,
                              void* d_out, int out_size, void* d_ws, size_t ws_size,
                              hipStream_t stream) {
    const float* x    = (const float*)d_in[0];
    const float* W    = (const float*)d_in[1];
    const float* bias = (const float*)d_in[2];
    float* out        = (float*)d_out;

    const size_t WSNEED = (size_t)DIM * 8 * 64 * 8 * sizeof(short);  // 4 MB
    dim3 block(256, 1, 1);
    dim3 grid((DIM / NTILES) * (BATCH / 64), 1, 1);                  // 32*32 = 1024

    if (ws_size >= WSNEED) {
        short* ws = (short*)d_ws;
        w_prep<<<dim3(DIM), block, 0, stream>>>(W, ws);
        split_linear_main<true><<<grid, block, 0, stream>>>(x, nullptr, ws, bias, out);
    } else {
        split_linear_main<false><<<grid, block, 0, stream>>>(x, W, nullptr, bias, out);
    }
}

// Round 14
// 109.044 us; speedup vs baseline: 1.2159x; 1.2159x over previous
//
#include <hip/hip_runtime.h>
#include <hip/hip_bf16.h>

#define DIM  512
#define FEAT 64
#define BATCH 2048

#define ROWS_PER_BLOCK 512
#define TILES_PER_WAVE 8   // ROWS_PER_BLOCK / (4 waves * 16 rows)

using bf16x8 = __attribute__((ext_vector_type(8))) short;
using f32x4  = __attribute__((ext_vector_type(4))) float;

typedef __attribute__((address_space(3))) float lds_f;
typedef __attribute__((address_space(1))) const float glb_f;

__device__ inline short f2bf(float f) {
    unsigned int u = __float_as_uint(f);
    u += 0x7fffu + ((u >> 16) & 1u);
    return (short)(u >> 16);
}

__device__ inline bf16x8 cvt8(float4 a, float4 b) {
    bf16x8 r;
    r[0] = f2bf(a.x); r[1] = f2bf(a.y); r[2] = f2bf(a.z); r[3] = f2bf(a.w);
    r[4] = f2bf(b.x); r[5] = f2bf(b.y); r[6] = f2bf(b.z); r[7] = f2bf(b.w);
    return r;
}

// R9 structure + store-side bias: LDS exactly 32KB -> 5 blocks/CU; VGPR ~56 <= 64
// cliff -> not VGPR-limited. arg2=4: cap 64 >= need (R3/R8 lesson: never cap below need).
__global__ __launch_bounds__(256, 4)
void split_linear_kernel(const float* __restrict__ x,
                         const float* __restrict__ W,
                         const float* __restrict__ bias,
                         float* __restrict__ out)
{
    // x staging AND out-transpose share slots: [wave][slot][16 rows][16 chunks],
    // 16B-chunk XOR(row&7) swizzle on both paths (R8/R9-verified). 32768 B exactly.
    __shared__ float xlds[4][2][1024];

    // chunked XCD swizzle, d fastest (R4/R9)
    const int id    = blockIdx.x;          // 0..2047
    const int xcd   = id & 7;
    const int chunk = id >> 3;             // 0..255
    const int nid   = xcd * 256 + chunk;
    const int d     = nid & (DIM - 1);
    const int b0    = (nid >> 9) * ROWS_PER_BLOCK;

    const int tid  = threadIdx.x;
    const int wave = tid >> 6;
    const int lane = tid & 63;
    const int lr   = lane & 15;   // A-row (g) / B-col (batch row) / store chunk
    const int lk   = lane >> 4;   // k-group

    // ---- W fragments in registers ----
    bf16x8 wf[2][4];
#pragma unroll
    for (int mt = 0; mt < 4; ++mt) {
        const float* wrow = W + ((size_t)d * FEAT + mt * 16 + lr) * FEAT + lk * 8;
#pragma unroll
        for (int ks = 0; ks < 2; ++ks) {
            float4 w0 = *(const float4*)(wrow + ks * 32);
            float4 w1 = *(const float4*)(wrow + ks * 32 + 4);
            wf[ks][mt] = cvt8(w0, w1);
        }
    }

    // ---- store-side bias: lane adds bias[d][cc*4..+3], cc = lane&15 = lr.
    //      4 VGPRs total (vs 16 at acc-init, vs 256B LDS for blds). ----
    const f32x4 bstore = *(const f32x4*)(bias + (size_t)d * FEAT + lr * 4);

    // ---- async dense stage: 4 instrs, each 4 rows x 256B fully covered ----
    auto stage = [&](int slot, int tt) {
#pragma unroll
        for (int i = 0; i < 4; ++i) {
            const int r = i * 4 + (lane >> 4);
            const int c = (lane & 15) ^ (r & 7);   // pre-swizzled source chunk
            const float* gp = x + ((size_t)(b0 + tt * 16 + r) * DIM + d) * FEAT + c * 4;
            __builtin_amdgcn_global_load_lds((glb_f*)gp,
                                             (lds_f*)&xlds[wave][slot][i * 256],
                                             16, 0, 0);
        }
    };

    stage(0, wave);            // tile 0
    stage(1, 4 + wave);        // tile 1

    for (int t = 0; t < TILES_PER_WAVE; ++t) {
        const int s = t & 1;
        // counted vmcnt (R9-verified): steady outstanding (old->new):
        // st(t-2),stage(t),st(t-1),stage(t+1)=16 -> keep newest 8.
        // t=0: [sg0,sg1]=8 -> keep 4. t=last: [st(t-2),sg(t),st(t-1)] -> keep 4.
        if (t == 0 || t == TILES_PER_WAVE - 1)
            asm volatile("s_waitcnt vmcnt(4)" ::: "memory");
        else
            asm volatile("s_waitcnt vmcnt(8)" ::: "memory");
        __builtin_amdgcn_sched_barrier(0);

        float* sl = &xlds[wave][s][0];
        float4 p0a = *(const float4*)&sl[lr * 64 + (((lk * 2 + 0) ^ (lr & 7)) << 2)];
        float4 p0b = *(const float4*)&sl[lr * 64 + (((lk * 2 + 1) ^ (lr & 7)) << 2)];
        float4 p1a = *(const float4*)&sl[lr * 64 + (((8 + lk * 2 + 0) ^ (lr & 7)) << 2)];
        float4 p1b = *(const float4*)&sl[lr * 64 + (((8 + lk * 2 + 1) ^ (lr & 7)) << 2)];

        bf16x8 af0 = cvt8(p0a, p0b);   // ks = 0
        bf16x8 af1 = cvt8(p1a, p1b);   // ks = 1

        f32x4 acc[4] = {{0.f,0.f,0.f,0.f},{0.f,0.f,0.f,0.f},
                        {0.f,0.f,0.f,0.f},{0.f,0.f,0.f,0.f}};
#pragma unroll
        for (int mt = 0; mt < 4; ++mt)
            acc[mt] = __builtin_amdgcn_mfma_f32_16x16x32_bf16(wf[0][mt], af0, acc[mt], 0, 0, 0);
#pragma unroll
        for (int mt = 0; mt < 4; ++mt)
            acc[mt] = __builtin_amdgcn_mfma_f32_16x16x32_bf16(wf[1][mt], af1, acc[mt], 0, 0, 0);

        // ---- transpose INTO the just-consumed slot (wave-private, DS in-order) ----
        // lane (lr,lk), mt holds out[row lr][g = mt*16+lk*4 ..+3] -> chunk c = mt*4+lk
#pragma unroll
        for (int mt = 0; mt < 4; ++mt) {
            const int c  = mt * 4 + lk;
            const int pc = c ^ (lr & 7);           // same swizzle as stage
            *(f32x4*)&sl[lr * 64 + pc * 4] = acc[mt];
        }

        // ---- dense NT store-back + bias: instr j covers rows j*4..+3, 256B/row ----
        const int orow0 = b0 + (t * 4 + wave) * 16;
#pragma unroll
        for (int j = 0; j < 4; ++j) {
            const int rr  = j * 4 + (lane >> 4);
            const int cc  = lane & 15;
            const int pc2 = cc ^ (rr & 7);
            f32x4 v = *(const f32x4*)&sl[rr * 64 + pc2 * 4];
            v += bstore;   // bias[d][cc*4..+3], row-independent
            __builtin_nontemporal_store(v,
                (f32x4*)(out + ((size_t)(orow0 + rr) * DIM + d) * FEAT + cc * 4));
        }
        __builtin_amdgcn_sched_barrier(0);   // pin the re-stage below the stores

        if (t + 2 < TILES_PER_WAVE)
            stage(s, (t + 2) * 4 + wave);    // reuse slot s (DMA lands after ds_reads)
    }
}

extern "C" void kernel_launch(void* const* d_in, const int* in_sizes, int n_in,
                              void* d_out, int out_size, void* d_ws, size_t ws_size,
                              hipStream_t stream) {
    const float* x    = (const float*)d_in[0];
    const float* W    = (const float*)d_in[1];
    const float* bias = (const float*)d_in[2];
    float* out        = (float*)d_out;

    dim3 grid(DIM * (BATCH / ROWS_PER_BLOCK), 1, 1);  // 2048 blocks (exploit 5/CU capacity)
    dim3 block(256, 1, 1);
    split_linear_kernel<<<grid, block, 0, stream>>>(x, W, bias, out);
}